// Round 5
// baseline (984.500 us; speedup 1.0000x reference)
//
#include <hip/hip_runtime.h>
#include <stdint.h>

#define B_ 2
#define N_ 4096
#define KNN 16
#define D_ 256
#define EPS_ 1e-5f
#define COLS_TOTAL (B_ * N_ * KNN)   // 131072

typedef unsigned short u16;
typedef unsigned long long u64;
typedef __bf16 bf16x8 __attribute__((ext_vector_type(8)));
typedef float f32x4 __attribute__((ext_vector_type(4)));

__device__ __forceinline__ float bu2f(u16 u) { return __uint_as_float(((unsigned)u) << 16); }
__device__ __forceinline__ u16 f2bu(float f) {
  unsigned u = __float_as_uint(f);
  unsigned r = (u + 0x7FFFu + ((u >> 16) & 1u)) >> 16;   // RNE
  return (u16)r;
}
__device__ __forceinline__ float rdl(const void* p, size_t i, int f) {
  return f ? bu2f(((const u16*)p)[i]) : ((const float*)p)[i];
}

// ---------- dtype detect (robustness; expected flag=0 i.e. f32) ----------
__global__ void detect_dtype(const unsigned* __restrict__ p, int* __restrict__ flag) {
  __shared__ int cnt;
  if (threadIdx.x == 0) cnt = 0;
  __syncthreads();
  unsigned w = p[threadIdx.x];
  unsigned e = (w >> 7) & 0xFFu;          // bf16 exponent field of LOW u16
  if (e >= 0x7Au && e <= 0x81u) atomicAdd(&cnt, 1);
  __syncthreads();
  if (threadIdx.x == 0) *flag = (cnt >= 128) ? 1 : 0;
}

// ---------- ingest raw scalars/weights into canonical f32 ----------
#define NSEG 29
struct Seg { const void* s; float* d; int n; };
struct SegTab { Seg seg[NSEG]; };
__global__ void ingest(SegTab t, const int* __restrict__ flagp, int total) {
  int tid = blockIdx.x * blockDim.x + threadIdx.x;
  if (tid >= total) return;
  int f = *flagp;
  int acc = 0, k = 0;
  for (k = 0; k < NSEG; k++) { if (tid < acc + t.seg[k].n) break; acc += t.seg[k].n; }
  int i = tid - acc;
  t.seg[k].d[i] = rdl(t.seg[k].s, i, f);
}

// ---------- compose: Wout(256x128) = Wo(256x256)@Wi(256x128); bout = Wo@bi + bo ----------
__global__ void compose(const float* __restrict__ Wo, const float* __restrict__ Wi,
                        const float* __restrict__ bi, const float* __restrict__ bo,
                        u16* __restrict__ Wout, float* __restrict__ bout) {
  int tid = blockIdx.x * blockDim.x + threadIdx.x;
  if (tid < 256 * 128) {
    int o = tid >> 7, i = tid & 127;
    float a = 0.f;
    for (int d = 0; d < 256; d++) a += Wo[o * 256 + d] * Wi[d * 128 + i];
    Wout[o * 128 + i] = f2bu(a);
  } else if (tid < 256 * 128 + 256) {
    int o = tid - 256 * 128;
    float a = bo[o];
    for (int d = 0; d < 256; d++) a += Wo[o * 256 + d] * bi[d];
    bout[o] = a;
  }
}

__global__ void quant(const float* __restrict__ s, u16* __restrict__ d, int n) {
  int t = blockIdx.x * blockDim.x + threadIdx.x;
  if (t < n) d[t] = f2bu(s[t]);
}

// ---------- transpose+quantize raw (B,128,N) -> (B*N,128) bf16 ----------
__global__ void transq(const void* __restrict__ raw, u16* __restrict__ out,
                       const int* __restrict__ flagp) {
  __shared__ u16 t[32][33];
  int f = *flagp;
  int b = blockIdx.z, c0 = blockIdx.y * 32, n0 = blockIdx.x * 32;
  int j = threadIdx.x & 31, i0 = threadIdx.x >> 5;
  for (int s = 0; s < 32; s += 8) {
    int i = i0 + s;
    t[i][j] = f2bu(rdl(raw, ((size_t)b * 128 + c0 + i) * N_ + n0 + j, f));
  }
  __syncthreads();
  int i = threadIdx.x & 31, j0 = threadIdx.x >> 5;
  for (int s = 0; s < 32; s += 8) {
    int jj = j0 + s;
    out[((size_t)b * N_ + n0 + jj) * 128 + c0 + i] = t[i][jj];
  }
}

// ---------- KNN ----------
__device__ __forceinline__ void knn_insert(u64* best, u64 key) {
#pragma unroll
  for (int j = 0; j < KNN; j++) {
    u64 old = best[j];
    bool lt = key < old;
    best[j] = lt ? key : old;
    key = lt ? old : key;
  }
}
__device__ __forceinline__ u64 knn_key(const float* px, float qx, float qy, float qz,
                                       float sqn, int m) {
  float cx = px[m], cy = px[N_ + m], cz = px[2 * N_ + m];
  float sqm = cx * cx + cy * cy + cz * cz;
  float dot = qx * cx + qy * cy + qz * cz;
  float d = (sqn + sqm) - 2.0f * dot;
  unsigned ub = __float_as_uint(d);
  ub = ((int)ub < 0) ? ~ub : (ub | 0x80000000u);
  return ((u64)ub << 32) | (unsigned)m;
}

__global__ void knn_partial(const float* __restrict__ pos, u64* __restrict__ part, int lognchk) {
  int nchk = 1 << lognchk;
  int tid = blockIdx.x * blockDim.x + threadIdx.x;
  if (tid >= (B_ * N_) << lognchk) return;
  int n = tid & (N_ - 1);
  int ch = (tid >> 12) & (nchk - 1);
  int b = tid >> (12 + lognchk);
  const float* px = pos + (size_t)b * 3 * N_;
  float qx = px[n], qy = px[N_ + n], qz = px[2 * N_ + n];
  float sqn = qx * qx + qy * qy + qz * qz;
  u64 best[KNN];
#pragma unroll
  for (int i = 0; i < KNN; i++) best[i] = ~0ull;
  int clen = N_ >> lognchk;
  int m0 = ch * clen;
  for (int m = m0; m < m0 + clen; ++m) knn_insert(best, knn_key(px, qx, qy, qz, sqn, m));
  u64* o = part + (size_t)tid * KNN;
#pragma unroll
  for (int i = 0; i < KNN; i++) o[i] = best[i];
}

__global__ void knn_merge(const u64* __restrict__ part, int* __restrict__ idx, int lognchk) {
  int tid = blockIdx.x * blockDim.x + threadIdx.x;
  if (tid >= B_ * N_) return;
  int n = tid & (N_ - 1);
  int b = tid >> 12;
  int nchk = 1 << lognchk;
  u64 best[KNN];
#pragma unroll
  for (int i = 0; i < KNN; i++) best[i] = ~0ull;
  for (int ch = 0; ch < nchk; ch++) {
    const u64* p = part + ((((size_t)((b << lognchk) + ch)) << 12) + n) * KNN;
    for (int e = 0; e < KNN; e++) knn_insert(best, p[e]);
  }
  int* o = idx + (size_t)tid * KNN;
#pragma unroll
  for (int i = 0; i < KNN; i++) o[i] = (int)(best[i] & 0xffffffffu);
}

// zero-scratch fallback: full scan per point
__global__ void knn_full(const float* __restrict__ pos, int* __restrict__ idx) {
  int tid = blockIdx.x * blockDim.x + threadIdx.x;
  if (tid >= B_ * N_) return;
  int n = tid & (N_ - 1);
  int b = tid >> 12;
  const float* px = pos + (size_t)b * 3 * N_;
  float qx = px[n], qy = px[N_ + n], qz = px[2 * N_ + n];
  float sqn = qx * qx + qy * qy + qz * qz;
  u64 best[KNN];
#pragma unroll
  for (int i = 0; i < KNN; i++) best[i] = ~0ull;
  for (int m = 0; m < N_; ++m) knn_insert(best, knn_key(px, qx, qy, qz, sqn, m));
  int* o = idx + (size_t)tid * KNN;
#pragma unroll
  for (int i = 0; i < KNN; i++) o[i] = (int)(best[i] & 0xffffffffu);
}

// ---------- scal (canonical f32) offsets ----------
#define SC_POS 0
#define SC_BLSQ 24576
#define SC_BLSO 24832
#define SC_BK 25088
#define SC_BQ 25344
#define SC_BV 25600
#define SC_WP1 25856
#define SC_BP1 26048
#define SC_G1 26112
#define SC_BT1 26176
#define SC_M1 26240
#define SC_V1 26304
#define SC_BP2 26368
#define SC_BA1 26624
#define SC_G2 27648
#define SC_BT2 28672
#define SC_M2 29696
#define SC_V2 30720
#define SC_BA2 31744
#define SC_BFIN 32000
#define SC_BQP 32128
#define SC_BKP 32384
#define SC_BVP 32640
#define SC_TOT 32896

// ---------- pos_mlp hidden ----------
__global__ void h1_build(const float* __restrict__ scal, const int* __restrict__ idx,
                         u16* __restrict__ h1c, int col_base) {
  int tid = blockIdx.x * blockDim.x + threadIdx.x;
  int col = tid >> 6, j = tid & 63;
  int gcol = col_base + col;
  int b = gcol >> 16;
  int rem = gcol & 65535;
  int n = rem >> 4, k = rem & 15;
  int id = idx[((size_t)(b * N_ + n)) * KNN + k];
  const float* px = scal + SC_POS + (size_t)b * 3 * N_;
  float pr0 = px[n] - px[id];
  float pr1 = px[N_ + n] - px[N_ + id];
  float pr2 = px[2 * N_ + n] - px[2 * N_ + id];
  const float* Wp1 = scal + SC_WP1;
  float h = (Wp1[j * 3 + 0] * pr0 + Wp1[j * 3 + 1] * pr1 + Wp1[j * 3 + 2] * pr2) + scal[SC_BP1 + j];
  float sc = scal[SC_G1 + j] * (1.0f / sqrtf(scal[SC_V1 + j] + EPS_));
  float sh = scal[SC_BT1 + j] - scal[SC_M1 + j] * sc;
  h = fmaxf(h * sc + sh, 0.f);
  h1c[(size_t)col * 64 + j] = f2bu(h);
}

// ---------- X[col][256] = query - key_gather + pe ----------
__global__ void x_build(const u16* __restrict__ query_t, const u16* __restrict__ key_t,
                        const u16* __restrict__ pe_c, const int* __restrict__ idx,
                        u16* __restrict__ Xc, int col_base) {
  int tid = blockIdx.x * blockDim.x + threadIdx.x;
  int col = tid >> 5, c0 = (tid & 31) * 8;
  int gcol = col_base + col;
  int b = gcol >> 16;
  int rem = gcol & 65535;
  int n = rem >> 4, k = rem & 15;
  int id = idx[((size_t)(b * N_ + n)) * KNN + k];
  uint4 qu = *(const uint4*)(query_t + ((size_t)(b * N_ + n)) * D_ + c0);
  uint4 ku = *(const uint4*)(key_t + ((size_t)(b * N_ + id)) * D_ + c0);
  uint4 pu = *(const uint4*)(pe_c + (size_t)col * D_ + c0);
  const u16 *qs = (const u16*)&qu, *ks = (const u16*)&ku, *ps = (const u16*)&pu;
  u16 o[8];
#pragma unroll
  for (int i = 0; i < 8; i++) o[i] = f2bu((bu2f(qs[i]) - bu2f(ks[i])) + bu2f(ps[i]));
  *(uint4*)(Xc + (size_t)col * D_ + c0) = *(uint4*)o;
}

// ---------- softmax over K + aggregate ----------
__global__ void softmax_agg(const u16* __restrict__ attn_c, const u16* __restrict__ pe_c,
                            const u16* __restrict__ value_t, u16* __restrict__ agg_c,
                            int col_base) {
  int tid = blockIdx.x * blockDim.x + threadIdx.x;
  int c = tid & 255, p = tid >> 8;
  int gcol = col_base + p * 16;
  int b = gcol >> 16;
  int rem = gcol & 65535;
  int n = rem >> 4;
  float x[16];
#pragma unroll
  for (int k = 0; k < 16; k++) x[k] = bu2f(attn_c[((size_t)(p * 16 + k)) * D_ + c]);
  float mx = x[0];
#pragma unroll
  for (int k = 1; k < 16; k++) mx = fmaxf(mx, x[k]);
  float s = 0.f;
#pragma unroll
  for (int k = 0; k < 16; k++) { x[k] = expf(x[k] - mx); s += x[k]; }
  float inv = 1.0f / s;
  float v = bu2f(value_t[((size_t)(b * N_ + n)) * D_ + c]);
  float acc = 0.f;
#pragma unroll
  for (int k = 0; k < 16; k++)
    acc += (x[k] * inv) * (v + bu2f(pe_c[((size_t)(p * 16 + k)) * D_ + c]));
  agg_c[(size_t)p * 256 + c] = f2bu(acc);
}

// ---------- MFMA GEMM: C[M x cols] = W[MxK] @ Bt[cols x K]^T + bias ----------
// epi 0: store (col, M) bf16 | epi 1: +BN+ReLU, (col, M) bf16
// epi 2: FINAL f32 store, (b, M, N_), point = pbase + col
__global__ __launch_bounds__(256) void gemm_bt(
    const u16* __restrict__ Wg, const u16* __restrict__ Bg, void* __restrict__ Outv,
    const float* __restrict__ bias,
    const float* __restrict__ bn_g, const float* __restrict__ bn_b,
    const float* __restrict__ bn_m, const float* __restrict__ bn_v,
    int M, int K, int epi, int pbase) {
  __shared__ __align__(16) u16 As[128 * 32];
  __shared__ __align__(16) u16 Bs[128 * 32];
  const int tid = threadIdx.x;
  const int mtile = blockIdx.y, ctile = blockIdx.x;
  const int wid = tid >> 6, lane = tid & 63;
  const int wm = wid >> 1, wc = wid & 1;
  const int l15 = lane & 15, quad = lane >> 4;
  f32x4 acc[4][4];
#pragma unroll
  for (int a = 0; a < 4; a++)
#pragma unroll
    for (int bb = 0; bb < 4; bb++) acc[a][bb] = (f32x4){0.f, 0.f, 0.f, 0.f};

  const int r0 = tid >> 2, q0 = tid & 3;
  for (int k0 = 0; k0 < K; k0 += 32) {
    __syncthreads();
    *(uint4*)(&As[(r0) * 32 + q0 * 8]) = *(const uint4*)(&Wg[((size_t)mtile * 128 + r0) * K + k0 + q0 * 8]);
    *(uint4*)(&As[(r0 + 64) * 32 + q0 * 8]) = *(const uint4*)(&Wg[((size_t)mtile * 128 + r0 + 64) * K + k0 + q0 * 8]);
    *(uint4*)(&Bs[(r0) * 32 + q0 * 8]) = *(const uint4*)(&Bg[((size_t)ctile * 128 + r0) * K + k0 + q0 * 8]);
    *(uint4*)(&Bs[(r0 + 64) * 32 + q0 * 8]) = *(const uint4*)(&Bg[((size_t)ctile * 128 + r0 + 64) * K + k0 + q0 * 8]);
    __syncthreads();
    bf16x8 af[4], bfr[4];
#pragma unroll
    for (int i = 0; i < 4; i++) {
      af[i] = *(const bf16x8*)(&As[(wm * 64 + i * 16 + l15) * 32 + quad * 8]);
      bfr[i] = *(const bf16x8*)(&Bs[(wc * 64 + i * 16 + l15) * 32 + quad * 8]);
    }
#pragma unroll
    for (int mi = 0; mi < 4; mi++)
#pragma unroll
      for (int ni = 0; ni < 4; ni++)
        acc[mi][ni] = __builtin_amdgcn_mfma_f32_16x16x32_bf16(af[mi], bfr[ni], acc[mi][ni], 0, 0, 0);
  }
  const int mbase = mtile * 128 + wm * 64;
  const int cbase = ctile * 128 + wc * 64;
#pragma unroll
  for (int mi = 0; mi < 4; mi++) {
#pragma unroll
    for (int ni = 0; ni < 4; ni++) {
      int m0 = mbase + mi * 16 + quad * 4;
      int c = cbase + ni * 16 + l15;
      if (epi == 2) {
        float* Of = (float*)Outv;
        int gp = pbase + c;
        int bb = gp >> 12, n = gp & (N_ - 1);
#pragma unroll
        for (int r = 0; r < 4; r++) {
          float v = acc[mi][ni][r] + bias[m0 + r];
          Of[((size_t)bb * M + (m0 + r)) * N_ + n] = v;   // f32 final output
        }
      } else {
        u16* O = (u16*)Outv;
        u16 pk[4];
#pragma unroll
        for (int r = 0; r < 4; r++) {
          int m = m0 + r;
          float v = acc[mi][ni][r] + bias[m];
          if (epi == 1) {
            float sc = bn_g[m] * (1.0f / sqrtf(bn_v[m] + EPS_));
            float sh = bn_b[m] - bn_m[m] * sc;
            v = fmaxf(v * sc + sh, 0.f);
          }
          pk[r] = f2bu(v);
        }
        *(uint2*)(&O[(size_t)c * M + m0]) = *(uint2*)pk;
      }
    }
  }
}

// wtmp (f32) offsets
#define WT_LSQ 0
#define WT_LSO 32768
#define WT_K 65536
#define WT_Q 131072
#define WT_V 196608
#define WT_P2 262144
#define WT_A1 278528
#define WT_A2 540672
#define WT_E 802816
#define WT_TOT 835584
// wbf (bf16) offsets
#define WB_QP 0
#define WB_KP 32768
#define WB_VP 65536
#define WB_P2 98304
#define WB_A1 114688
#define WB_A2 376832
#define WB_E 638976
#define WB_TOT 671744

extern "C" void kernel_launch(void* const* d_in, const int* in_sizes, int n_in,
                              void* d_out, int out_size, void* d_ws, size_t ws_size,
                              hipStream_t stream) {
  (void)in_sizes; (void)n_in; (void)out_size;
  char* wsb = (char*)d_ws;
  size_t off = 0;
  auto alloc = [&](size_t bytes) -> void* {
    void* p = wsb + off;
    off = (off + bytes + 255) & ~(size_t)255;
    return p;
  };
  // persistent (~14 MB)
  int* flag = (int*)alloc(256);
  int* idx = (int*)alloc((size_t)B_ * N_ * KNN * 4);
  u16* wbf = (u16*)alloc((size_t)WB_TOT * 2);
  float* scal = (float*)alloc((size_t)SC_TOT * 4);
  u16* key_t = (u16*)alloc((size_t)B_ * N_ * D_ * 2);
  u16* query_t = (u16*)alloc((size_t)B_ * N_ * D_ * 2);
  u16* value_t = (u16*)alloc((size_t)B_ * N_ * D_ * 2);
  size_t persist = off;
  size_t avail = (ws_size > persist) ? (ws_size - persist) : 0;

  // overlay (time-disjoint): wtmp -> qp_t/obj_t -> knn_part -> chunk bufs
  char* ovl = wsb + persist;
  float* wtmp = (float*)ovl;
  u16* qp_t = (u16*)ovl;
  u16* obj_t = (u16*)(ovl + (size_t)B_ * N_ * 128 * 2 + 256);
  u64* knn_part = (u64*)ovl;

  int lognchk = -1;   // -1 => zero-scratch knn_full
  for (int lg = 3; lg >= 0; lg--) {
    if ((((size_t)B_ * N_ * KNN * 8) << lg) <= avail) { lognchk = lg; break; }
  }
  int cch = 2048;
  const int cands[7] = {131072, 65536, 32768, 16384, 8192, 4096, 2048};
  for (int i = 0; i < 7; i++) {
    size_t need = (size_t)cands[i] * (64 + 256 + 256 + 256 + 1024) * 2
                + (size_t)(cands[i] / 16) * 256 * 2 + 8 * 256;
    if (need <= avail) { cch = cands[i]; break; }
  }
  off = persist;
  u16* h1_c = (u16*)alloc((size_t)cch * 64 * 2);
  u16* pe_c = (u16*)alloc((size_t)cch * 256 * 2);
  u16* X_c = (u16*)alloc((size_t)cch * 256 * 2);
  u16* h_c = (u16*)alloc((size_t)cch * 1024 * 2);
  u16* attn_c = (u16*)alloc((size_t)cch * 256 * 2);
  u16* agg_c = (u16*)alloc((size_t)(cch / 16) * 256 * 2);

  // 1. dtype flag
  detect_dtype<<<1, 256, 0, stream>>>((const unsigned*)d_in[1], flag);

  // 2. ingest canonical f32
  SegTab st;
  int si = 0;
  auto seg = [&](int di, float* d, int n) { st.seg[si].s = d_in[di]; st.seg[si].d = d; st.seg[si].n = n; si++; };
  seg(1, scal + SC_POS, 24576);
  seg(4, scal + SC_BLSQ, 256); seg(6, scal + SC_BLSO, 256);
  seg(8, scal + SC_BK, 256); seg(10, scal + SC_BQ, 256); seg(12, scal + SC_BV, 256);
  seg(13, scal + SC_WP1, 192); seg(14, scal + SC_BP1, 64); seg(15, scal + SC_G1, 64);
  seg(16, scal + SC_BT1, 64); seg(17, scal + SC_M1, 64); seg(18, scal + SC_V1, 64);
  seg(20, scal + SC_BP2, 256); seg(22, scal + SC_BA1, 1024);
  seg(23, scal + SC_G2, 1024); seg(24, scal + SC_BT2, 1024); seg(25, scal + SC_M2, 1024);
  seg(26, scal + SC_V2, 1024); seg(28, scal + SC_BA2, 256); seg(30, scal + SC_BFIN, 128);
  seg(3, wtmp + WT_LSQ, 32768); seg(5, wtmp + WT_LSO, 32768);
  seg(7, wtmp + WT_K, 65536); seg(9, wtmp + WT_Q, 65536); seg(11, wtmp + WT_V, 65536);
  seg(19, wtmp + WT_P2, 16384); seg(21, wtmp + WT_A1, 262144);
  seg(27, wtmp + WT_A2, 262144); seg(29, wtmp + WT_E, 32768);
  int total = 32128 + WT_TOT;
  ingest<<<(total + 255) / 256, 256, 0, stream>>>(st, flag, total);

  // 3. compose q/k/v chains
  compose<<<130, 256, 0, stream>>>(wtmp + WT_Q, wtmp + WT_LSQ, scal + SC_BLSQ, scal + SC_BQ, wbf + WB_QP, scal + SC_BQP);
  compose<<<130, 256, 0, stream>>>(wtmp + WT_K, wtmp + WT_LSO, scal + SC_BLSO, scal + SC_BK, wbf + WB_KP, scal + SC_BKP);
  compose<<<130, 256, 0, stream>>>(wtmp + WT_V, wtmp + WT_LSO, scal + SC_BLSO, scal + SC_BV, wbf + WB_VP, scal + SC_BVP);
  // 4. quantize Wp2,Wa1,Wa2,We
  quant<<<(573440 + 255) / 256, 256, 0, stream>>>(wtmp + WT_P2, wbf + WB_P2, 573440);

  // 5. transpose inputs (wtmp dead)
  transq<<<dim3(N_ / 32, 4, B_), 256, 0, stream>>>(d_in[2], qp_t, flag);
  transq<<<dim3(N_ / 32, 4, B_), 256, 0, stream>>>(d_in[0], obj_t, flag);

  auto gemm = [&](const u16* W, const u16* Bt, void* O, const float* bias, int M, int K,
                  int cols, int epi, int pbase,
                  const float* gg, const float* bb, const float* mm, const float* vv) {
    gemm_bt<<<dim3(cols / 128, M / 128), 256, 0, stream>>>(W, Bt, O, bias, gg, bb, mm, vv, M, K, epi, pbase);
  };
  // 6. q/k/v projections (composed, K=128)
  gemm(wbf + WB_QP, qp_t, query_t, scal + SC_BQP, 256, 128, B_ * N_, 0, 0, nullptr, nullptr, nullptr, nullptr);
  gemm(wbf + WB_KP, obj_t, key_t, scal + SC_BKP, 256, 128, B_ * N_, 0, 0, nullptr, nullptr, nullptr, nullptr);
  gemm(wbf + WB_VP, obj_t, value_t, scal + SC_BVP, 256, 128, B_ * N_, 0, 0, nullptr, nullptr, nullptr, nullptr);

  // 7. KNN (qp_t/obj_t dead)
  if (lognchk >= 0) {
    knn_partial<<<((B_ * N_) << lognchk) / 256, 256, 0, stream>>>(scal + SC_POS, knn_part, lognchk);
    knn_merge<<<(B_ * N_) / 256, 256, 0, stream>>>(knn_part, idx, lognchk);
  } else {
    knn_full<<<(B_ * N_) / 256, 256, 0, stream>>>(scal + SC_POS, idx);
  }

  // 8. chunk loop (knn_part dead)
  for (int cb = 0; cb < COLS_TOTAL; cb += cch) {
    h1_build<<<(cch * 64) / 256, 256, 0, stream>>>(scal, idx, h1_c, cb);
    gemm(wbf + WB_P2, h1_c, pe_c, scal + SC_BP2, 256, 64, cch, 0, 0, nullptr, nullptr, nullptr, nullptr);
    x_build<<<(cch * 32) / 256, 256, 0, stream>>>(query_t, key_t, pe_c, idx, X_c, cb);
    gemm(wbf + WB_A1, X_c, h_c, scal + SC_BA1, 1024, 256, cch, 1, 0,
         scal + SC_G2, scal + SC_BT2, scal + SC_M2, scal + SC_V2);
    gemm(wbf + WB_A2, h_c, attn_c, scal + SC_BA2, 256, 1024, cch, 0, 0, nullptr, nullptr, nullptr, nullptr);
    softmax_agg<<<cch / 16, 256, 0, stream>>>(attn_c, pe_c, value_t, agg_c, cb);
    gemm(wbf + WB_E, agg_c, d_out, scal + SC_BFIN, 128, 256, cch / 16, 2, cb / 16,
         nullptr, nullptr, nullptr, nullptr);
  }
}

// Round 6
// 787.015 us; speedup vs baseline: 1.2509x; 1.2509x over previous
//
#include <hip/hip_runtime.h>
#include <stdint.h>

#define B_ 2
#define N_ 4096
#define KNN 16
#define D_ 256
#define EPS_ 1e-5f
#define COLS_TOTAL (B_ * N_ * KNN)   // 131072

typedef unsigned short u16;
typedef unsigned long long u64;
typedef __bf16 bf16x8 __attribute__((ext_vector_type(8)));
typedef float f32x4 __attribute__((ext_vector_type(4)));

__device__ __forceinline__ float bu2f(u16 u) { return __uint_as_float(((unsigned)u) << 16); }
__device__ __forceinline__ u16 f2bu(float f) {
  unsigned u = __float_as_uint(f);
  unsigned r = (u + 0x7FFFu + ((u >> 16) & 1u)) >> 16;   // RNE
  return (u16)r;
}
__device__ __forceinline__ float rdl(const void* p, size_t i, int f) {
  return f ? bu2f(((const u16*)p)[i]) : ((const float*)p)[i];
}
// async global->LDS, 16B per lane (m97 pattern)
__device__ __forceinline__ void gl16(const u16* g, u16* l) {
  __builtin_amdgcn_global_load_lds((const __attribute__((address_space(1))) unsigned int*)g,
                                   (__attribute__((address_space(3))) unsigned int*)l,
                                   16, 0, 0);
}

// ---------- dtype detect ----------
__global__ void detect_dtype(const unsigned* __restrict__ p, int* __restrict__ flag) {
  __shared__ int cnt;
  if (threadIdx.x == 0) cnt = 0;
  __syncthreads();
  unsigned w = p[threadIdx.x];
  unsigned e = (w >> 7) & 0xFFu;
  if (e >= 0x7Au && e <= 0x81u) atomicAdd(&cnt, 1);
  __syncthreads();
  if (threadIdx.x == 0) *flag = (cnt >= 128) ? 1 : 0;
}

// ---------- ingest ----------
#define NSEG 29
struct Seg { const void* s; float* d; int n; };
struct SegTab { Seg seg[NSEG]; };
__global__ void ingest(SegTab t, const int* __restrict__ flagp, int total) {
  int tid = blockIdx.x * blockDim.x + threadIdx.x;
  if (tid >= total) return;
  int f = *flagp;
  int acc = 0, k = 0;
  for (k = 0; k < NSEG; k++) { if (tid < acc + t.seg[k].n) break; acc += t.seg[k].n; }
  int i = tid - acc;
  t.seg[k].d[i] = rdl(t.seg[k].s, i, f);
}

// ---------- compose q/k/v chain ----------
__global__ void compose(const float* __restrict__ Wo, const float* __restrict__ Wi,
                        const float* __restrict__ bi, const float* __restrict__ bo,
                        u16* __restrict__ Wout, float* __restrict__ bout) {
  int tid = blockIdx.x * blockDim.x + threadIdx.x;
  if (tid < 256 * 128) {
    int o = tid >> 7, i = tid & 127;
    float a = 0.f;
    for (int d = 0; d < 256; d++) a += Wo[o * 256 + d] * Wi[d * 128 + i];
    Wout[o * 128 + i] = f2bu(a);
  } else if (tid < 256 * 128 + 256) {
    int o = tid - 256 * 128;
    float a = bo[o];
    for (int d = 0; d < 256; d++) a += Wo[o * 256 + d] * bi[d];
    bout[o] = a;
  }
}

__global__ void quant(const float* __restrict__ s, u16* __restrict__ d, int n) {
  int t = blockIdx.x * blockDim.x + threadIdx.x;
  if (t < n) d[t] = f2bu(s[t]);
}

// ---------- scal (canonical f32) offsets ----------
#define SC_POS 0
#define SC_BLSQ 24576
#define SC_BLSO 24832
#define SC_BK 25088
#define SC_BQ 25344
#define SC_BV 25600
#define SC_WP1 25856
#define SC_BP1 26048
#define SC_G1 26112
#define SC_BT1 26176
#define SC_M1 26240
#define SC_V1 26304
#define SC_BP2 26368
#define SC_BA1 26624
#define SC_G2 27648
#define SC_BT2 28672
#define SC_M2 29696
#define SC_V2 30720
#define SC_BA2 31744
#define SC_BFIN 32000
#define SC_BQP 32128
#define SC_BKP 32384
#define SC_BVP 32640
// folded BN constants (bnprep)
#define SC_W1S 32896   // 192: Wp1 * sc1
#define SC_C1  33088   // 64:  bp1*sc1 + (bt1 - m1*sc1)
#define SC_ASC 33152   // 1024: g2/sqrt(v2+eps)
#define SC_ASH 34176   // 1024: ba1*asc + (bt2 - m2*asc)
#define SC_TOT 35200

// ---------- fold BN params ----------
__global__ void bnprep(float* __restrict__ scal) {
  int t = blockIdx.x * blockDim.x + threadIdx.x;
  if (t < 1024) {
    float sc = scal[SC_G2 + t] * (1.0f / sqrtf(scal[SC_V2 + t] + EPS_));
    scal[SC_ASC + t] = sc;
    scal[SC_ASH + t] = scal[SC_BA1 + t] * sc + (scal[SC_BT2 + t] - scal[SC_M2 + t] * sc);
  }
  if (t < 64) {
    float sc1 = scal[SC_G1 + t] * (1.0f / sqrtf(scal[SC_V1 + t] + EPS_));
    scal[SC_C1 + t] = scal[SC_BP1 + t] * sc1 + (scal[SC_BT1 + t] - scal[SC_M1 + t] * sc1);
    for (int i = 0; i < 3; i++) scal[SC_W1S + t * 3 + i] = scal[SC_WP1 + t * 3 + i] * sc1;
  }
}

// ---------- transpose+quantize raw (B,128,N) -> (B*N,128) bf16 ----------
__global__ void transq(const void* __restrict__ raw, u16* __restrict__ out,
                       const int* __restrict__ flagp) {
  __shared__ u16 t[32][33];
  int f = *flagp;
  int b = blockIdx.z, c0 = blockIdx.y * 32, n0 = blockIdx.x * 32;
  int j = threadIdx.x & 31, i0 = threadIdx.x >> 5;
  for (int s = 0; s < 32; s += 8) {
    int i = i0 + s;
    t[i][j] = f2bu(rdl(raw, ((size_t)b * 128 + c0 + i) * N_ + n0 + j, f));
  }
  __syncthreads();
  int i = threadIdx.x & 31, j0 = threadIdx.x >> 5;
  for (int s = 0; s < 32; s += 8) {
    int jj = j0 + s;
    out[((size_t)b * N_ + n0 + jj) * 128 + c0 + i] = t[i][jj];
  }
}

// ---------- KNN ----------
__device__ __forceinline__ void knn_insert(u64* best, u64 key) {
#pragma unroll
  for (int j = 0; j < KNN; j++) {
    u64 old = best[j];
    bool lt = key < old;
    best[j] = lt ? key : old;
    key = lt ? old : key;
  }
}
__device__ __forceinline__ u64 knn_key(const float* px, float qx, float qy, float qz,
                                       float sqn, int m) {
  float cx = px[m], cy = px[N_ + m], cz = px[2 * N_ + m];
  float sqm = cx * cx + cy * cy + cz * cz;
  float dot = qx * cx + qy * cy + qz * cz;
  float d = (sqn + sqm) - 2.0f * dot;
  unsigned ub = __float_as_uint(d);
  ub = ((int)ub < 0) ? ~ub : (ub | 0x80000000u);
  return ((u64)ub << 32) | (unsigned)m;
}

__global__ void knn_partial(const float* __restrict__ pos, u64* __restrict__ part, int lognchk) {
  int nchk = 1 << lognchk;
  int tid = blockIdx.x * blockDim.x + threadIdx.x;
  if (tid >= (B_ * N_) << lognchk) return;
  int n = tid & (N_ - 1);
  int ch = (tid >> 12) & (nchk - 1);
  int b = tid >> (12 + lognchk);
  const float* px = pos + (size_t)b * 3 * N_;
  float qx = px[n], qy = px[N_ + n], qz = px[2 * N_ + n];
  float sqn = qx * qx + qy * qy + qz * qz;
  u64 best[KNN];
#pragma unroll
  for (int i = 0; i < KNN; i++) best[i] = ~0ull;
  int clen = N_ >> lognchk;
  int m0 = ch * clen;
  for (int m = m0; m < m0 + clen; ++m) knn_insert(best, knn_key(px, qx, qy, qz, sqn, m));
  u64* o = part + (size_t)tid * KNN;
#pragma unroll
  for (int i = 0; i < KNN; i++) o[i] = best[i];
}

__global__ void knn_merge(const u64* __restrict__ part, int* __restrict__ idx, int lognchk) {
  int tid = blockIdx.x * blockDim.x + threadIdx.x;
  if (tid >= B_ * N_) return;
  int n = tid & (N_ - 1);
  int b = tid >> 12;
  int nchk = 1 << lognchk;
  u64 best[KNN];
#pragma unroll
  for (int i = 0; i < KNN; i++) best[i] = ~0ull;
  for (int ch = 0; ch < nchk; ch++) {
    const u64* p = part + ((((size_t)((b << lognchk) + ch)) << 12) + n) * KNN;
    for (int e = 0; e < KNN; e++) knn_insert(best, p[e]);
  }
  int* o = idx + (size_t)tid * KNN;
#pragma unroll
  for (int i = 0; i < KNN; i++) o[i] = (int)(best[i] & 0xffffffffu);
}

__global__ void knn_full(const float* __restrict__ pos, int* __restrict__ idx) {
  int tid = blockIdx.x * blockDim.x + threadIdx.x;
  if (tid >= B_ * N_) return;
  int n = tid & (N_ - 1);
  int b = tid >> 12;
  const float* px = pos + (size_t)b * 3 * N_;
  float qx = px[n], qy = px[N_ + n], qz = px[2 * N_ + n];
  float sqn = qx * qx + qy * qy + qz * qz;
  u64 best[KNN];
#pragma unroll
  for (int i = 0; i < KNN; i++) best[i] = ~0ull;
  for (int m = 0; m < N_; ++m) knn_insert(best, knn_key(px, qx, qy, qz, sqn, m));
  int* o = idx + (size_t)tid * KNN;
#pragma unroll
  for (int i = 0; i < KNN; i++) o[i] = (int)(best[i] & 0xffffffffu);
}

// ---------- q/k/v projection GEMM (proven): C[M x cols] = W@Bt^T + bias -> (col,M) bf16 ----------
__global__ __launch_bounds__(256) void gemm_bt(
    const u16* __restrict__ Wg, const u16* __restrict__ Bg, u16* __restrict__ Out,
    const float* __restrict__ bias, int M, int K) {
  __shared__ __align__(16) u16 As[128 * 32];
  __shared__ __align__(16) u16 Bs[128 * 32];
  const int tid = threadIdx.x;
  const int mtile = blockIdx.y, ctile = blockIdx.x;
  const int wid = tid >> 6, lane = tid & 63;
  const int wm = wid >> 1, wc = wid & 1;
  const int l15 = lane & 15, quad = lane >> 4;
  f32x4 acc[4][4];
#pragma unroll
  for (int a = 0; a < 4; a++)
#pragma unroll
    for (int bb = 0; bb < 4; bb++) acc[a][bb] = (f32x4){0.f, 0.f, 0.f, 0.f};
  const int r0 = tid >> 2, q0 = tid & 3;
  for (int k0 = 0; k0 < K; k0 += 32) {
    __syncthreads();
    *(uint4*)(&As[(r0) * 32 + q0 * 8]) = *(const uint4*)(&Wg[((size_t)mtile * 128 + r0) * K + k0 + q0 * 8]);
    *(uint4*)(&As[(r0 + 64) * 32 + q0 * 8]) = *(const uint4*)(&Wg[((size_t)mtile * 128 + r0 + 64) * K + k0 + q0 * 8]);
    *(uint4*)(&Bs[(r0) * 32 + q0 * 8]) = *(const uint4*)(&Bg[((size_t)ctile * 128 + r0) * K + k0 + q0 * 8]);
    *(uint4*)(&Bs[(r0 + 64) * 32 + q0 * 8]) = *(const uint4*)(&Bg[((size_t)ctile * 128 + r0 + 64) * K + k0 + q0 * 8]);
    __syncthreads();
    bf16x8 af[4], bfr[4];
#pragma unroll
    for (int i = 0; i < 4; i++) {
      af[i] = *(const bf16x8*)(&As[(wm * 64 + i * 16 + l15) * 32 + quad * 8]);
      bfr[i] = *(const bf16x8*)(&Bs[(wc * 64 + i * 16 + l15) * 32 + quad * 8]);
    }
#pragma unroll
    for (int mi = 0; mi < 4; mi++)
#pragma unroll
      for (int ni = 0; ni < 4; ni++)
        acc[mi][ni] = __builtin_amdgcn_mfma_f32_16x16x32_bf16(af[mi], bfr[ni], acc[mi][ni], 0, 0, 0);
  }
  const int mbase = mtile * 128 + wm * 64;
  const int cbase = ctile * 128 + wc * 64;
#pragma unroll
  for (int mi = 0; mi < 4; mi++) {
#pragma unroll
    for (int ni = 0; ni < 4; ni++) {
      int m0 = mbase + mi * 16 + quad * 4;
      int c = cbase + ni * 16 + l15;
      u16 pk[4];
#pragma unroll
      for (int r = 0; r < 4; r++) pk[r] = f2bu(acc[mi][ni][r] + bias[m0 + r]);
      *(uint2*)(&Out[(size_t)c * M + m0]) = *(uint2*)pk;
    }
  }
}

// ================= MEGA: pos_mlp(P2) + X + attn_mlp(A1,A2) + softmax + agg + linear_end =================
// 64 columns (4 points) per block, 512 threads (8 waves).
// LDS u16 offsets:
#define XS_OFF  0        // 64 x 264  (X, later reused for attn)
#define PES_OFF 16896    // 64 x 264  (pe, bf16)
#define HS_OFF  33792    // 64 x 136  (h slice, bf16)
#define H1S_OFF 42496    // 64 x 72   (h1, bf16)
#define WST_OFF 47104    // 16KB weight staging (8192 u16)
#define SM_TOT  55296

__global__ __launch_bounds__(512, 2) void mega(
    const float* __restrict__ scal, const int* __restrict__ idx,
    const u16* __restrict__ wbf,
    const u16* __restrict__ query_t, const u16* __restrict__ key_t,
    const u16* __restrict__ value_t, float* __restrict__ out,
    const u16* __restrict__ Wp2g, const u16* __restrict__ Wa1g,
    const u16* __restrict__ Wa2g, const u16* __restrict__ Weg) {
  __shared__ __align__(16) u16 sm[SM_TOT];
  __shared__ __align__(16) float aggs[1024];   // [m][pt]
  const int tid = threadIdx.x;
  const int w = tid >> 6, lane = tid & 63;
  const int l15 = lane & 15, quad = lane >> 4;
  const int gcol0 = blockIdx.x * 64;
  const int b = gcol0 >> 16;
  const int n0 = (gcol0 & 65535) >> 4;         // 4 points n0..n0+3
  const int wmg = w & 3, wcg = w >> 2;

  // ---- Phase 0: h1 (pos_mlp layer 1, BN folded) ----
  {
    int col = tid >> 3, jg = (tid & 7) * 8;
    int n = n0 + (col >> 4), k = col & 15;
    int id = idx[((size_t)(b * N_ + n)) * KNN + k];
    const float* px = scal + SC_POS + (size_t)b * 3 * N_;
    float pr0 = px[n] - px[id];
    float pr1 = px[N_ + n] - px[N_ + id];
    float pr2 = px[2 * N_ + n] - px[2 * N_ + id];
    u16 o[8];
#pragma unroll
    for (int e = 0; e < 8; e++) {
      int j = jg + e;
      float v = scal[SC_W1S + j * 3] * pr0 + scal[SC_W1S + j * 3 + 1] * pr1 +
                scal[SC_W1S + j * 3 + 2] * pr2 + scal[SC_C1 + j];
      o[e] = f2bu(fmaxf(v, 0.f));
    }
    *(uint4*)(&sm[H1S_OFF + col * 72 + jg]) = *(uint4*)o;
  }
  __syncthreads();

  // ---- Phase 1: P2 -> pe (M=256, K=64) ----
  {
    f32x4 pacc[4][2];
#pragma unroll
    for (int mi = 0; mi < 4; mi++)
#pragma unroll
      for (int ni = 0; ni < 2; ni++) pacc[mi][ni] = (f32x4){0.f, 0.f, 0.f, 0.f};
    for (int k0 = 0; k0 < 64; k0 += 32) {
#pragma unroll
      for (int it = 0; it < 2; it++) {
        int c = tid + it * 512;
        int row = c >> 2, sub = c & 3;
        gl16(Wp2g + (size_t)row * 64 + k0 + sub * 8, &sm[WST_OFF + c * 8]);
      }
      __syncthreads();
      bf16x8 bfr[2];
#pragma unroll
      for (int ni = 0; ni < 2; ni++)
        bfr[ni] = *(const bf16x8*)(&sm[H1S_OFF + (wcg * 32 + ni * 16 + l15) * 72 + k0 + quad * 8]);
#pragma unroll
      for (int mi = 0; mi < 4; mi++) {
        bf16x8 af = *(const bf16x8*)(&sm[WST_OFF + (wmg * 64 + mi * 16 + l15) * 32 + quad * 8]);
#pragma unroll
        for (int ni = 0; ni < 2; ni++)
          pacc[mi][ni] = __builtin_amdgcn_mfma_f32_16x16x32_bf16(af, bfr[ni], pacc[mi][ni], 0, 0, 0);
      }
      __syncthreads();
    }
#pragma unroll
    for (int mi = 0; mi < 4; mi++)
#pragma unroll
      for (int ni = 0; ni < 2; ni++) {
        int m0 = wmg * 64 + mi * 16 + quad * 4;
        int col = wcg * 32 + ni * 16 + l15;
        u16 pk[4];
#pragma unroll
        for (int r = 0; r < 4; r++) pk[r] = f2bu(pacc[mi][ni][r] + scal[SC_BP2 + m0 + r]);
        *(uint2*)(&sm[PES_OFF + col * 264 + m0]) = *(uint2*)pk;
      }
  }
  __syncthreads();

  // ---- Phase 2: X = query - key_gather + pe ----
#pragma unroll
  for (int it = 0; it < 4; it++) {
    int g = tid + it * 512;
    int col = g >> 5, dg = (g & 31) * 8;
    int n = n0 + (col >> 4), k = col & 15;
    int id = idx[((size_t)(b * N_ + n)) * KNN + k];
    uint4 qu = *(const uint4*)(query_t + ((size_t)(b * N_ + n)) * D_ + dg);
    uint4 ku = *(const uint4*)(key_t + ((size_t)(b * N_ + id)) * D_ + dg);
    uint4 pu = *(const uint4*)(&sm[PES_OFF + col * 264 + dg]);
    const u16 *qs = (const u16*)&qu, *ks = (const u16*)&ku, *ps = (const u16*)&pu;
    u16 o[8];
#pragma unroll
    for (int e = 0; e < 8; e++) o[e] = f2bu((bu2f(qs[e]) - bu2f(ks[e])) + bu2f(ps[e]));
    *(uint4*)(&sm[XS_OFF + col * 264 + dg]) = *(uint4*)o;
  }
  __syncthreads();

  // ---- Phase 3/4: A1 (h slice) + A2 accumulate, per 128-row h block ----
  f32x4 aacc[4][2];
#pragma unroll
  for (int mi = 0; mi < 4; mi++)
#pragma unroll
    for (int ni = 0; ni < 2; ni++) aacc[mi][ni] = (f32x4){0.f, 0.f, 0.f, 0.f};

  for (int hb = 0; hb < 8; hb++) {
    f32x4 hacc[2][2];
#pragma unroll
    for (int mi = 0; mi < 2; mi++)
#pragma unroll
      for (int ni = 0; ni < 2; ni++) hacc[mi][ni] = (f32x4){0.f, 0.f, 0.f, 0.f};
    for (int k0 = 0; k0 < 256; k0 += 32) {
      {
        int row = tid >> 2, sub = tid & 3;
        gl16(Wa1g + ((size_t)(hb * 128 + row)) * 256 + k0 + sub * 8, &sm[WST_OFF + tid * 8]);
      }
      __syncthreads();
      bf16x8 bx[2];
#pragma unroll
      for (int ni = 0; ni < 2; ni++)
        bx[ni] = *(const bf16x8*)(&sm[XS_OFF + (wcg * 32 + ni * 16 + l15) * 264 + k0 + quad * 8]);
#pragma unroll
      for (int mi = 0; mi < 2; mi++) {
        bf16x8 af = *(const bf16x8*)(&sm[WST_OFF + (wmg * 32 + mi * 16 + l15) * 32 + quad * 8]);
#pragma unroll
        for (int ni = 0; ni < 2; ni++)
          hacc[mi][ni] = __builtin_amdgcn_mfma_f32_16x16x32_bf16(af, bx[ni], hacc[mi][ni], 0, 0, 0);
      }
      __syncthreads();
    }
    // h epilogue: BN+ReLU (folded) -> hs
#pragma unroll
    for (int mi = 0; mi < 2; mi++)
#pragma unroll
      for (int ni = 0; ni < 2; ni++) {
        int hr0 = wmg * 32 + mi * 16 + quad * 4;
        int mh = hb * 128 + hr0;
        int col = wcg * 32 + ni * 16 + l15;
        u16 pk[4];
#pragma unroll
        for (int r = 0; r < 4; r++) {
          float v = hacc[mi][ni][r] * scal[SC_ASC + mh + r] + scal[SC_ASH + mh + r];
          pk[r] = f2bu(fmaxf(v, 0.f));
        }
        *(uint2*)(&sm[HS_OFF + col * 136 + hr0]) = *(uint2*)pk;
      }
    __syncthreads();
    // A2 over this h block (K=128)
    for (int k0 = 0; k0 < 128; k0 += 32) {
#pragma unroll
      for (int it = 0; it < 2; it++) {
        int c = tid + it * 512;
        int row = c >> 2, sub = c & 3;
        gl16(Wa2g + (size_t)row * 1024 + hb * 128 + k0 + sub * 8, &sm[WST_OFF + c * 8]);
      }
      __syncthreads();
      bf16x8 bh[2];
#pragma unroll
      for (int ni = 0; ni < 2; ni++)
        bh[ni] = *(const bf16x8*)(&sm[HS_OFF + (wcg * 32 + ni * 16 + l15) * 136 + k0 + quad * 8]);
#pragma unroll
      for (int mi = 0; mi < 4; mi++) {
        bf16x8 af = *(const bf16x8*)(&sm[WST_OFF + (wmg * 64 + mi * 16 + l15) * 32 + quad * 8]);
#pragma unroll
        for (int ni = 0; ni < 2; ni++)
          aacc[mi][ni] = __builtin_amdgcn_mfma_f32_16x16x32_bf16(af, bh[ni], aacc[mi][ni], 0, 0, 0);
      }
      __syncthreads();
    }
  }

  // ---- Phase 5: attn (+ba2) -> LDS (reuse XS region) ----
#pragma unroll
  for (int mi = 0; mi < 4; mi++)
#pragma unroll
    for (int ni = 0; ni < 2; ni++) {
      int m0 = wmg * 64 + mi * 16 + quad * 4;
      int col = wcg * 32 + ni * 16 + l15;
      u16 pk[4];
#pragma unroll
      for (int r = 0; r < 4; r++) pk[r] = f2bu(aacc[mi][ni][r] + scal[SC_BA2 + m0 + r]);
      *(uint2*)(&sm[XS_OFF + col * 264 + m0]) = *(uint2*)pk;
    }
  __syncthreads();

  // ---- Phase 6: softmax over 16 neighbors + aggregate ----
#pragma unroll
  for (int it = 0; it < 2; it++) {
    int e = tid + it * 512;          // 1024 = 256 m x 4 pt
    int m = e >> 2, pt = e & 3;
    float a[16];
#pragma unroll
    for (int k = 0; k < 16; k++) a[k] = bu2f(sm[XS_OFF + (pt * 16 + k) * 264 + m]);
    float mx = a[0];
#pragma unroll
    for (int k = 1; k < 16; k++) mx = fmaxf(mx, a[k]);
    float s = 0.f;
#pragma unroll
    for (int k = 0; k < 16; k++) { a[k] = expf(a[k] - mx); s += a[k]; }
    float inv = 1.0f / s;
    float acc = 0.f;
#pragma unroll
    for (int k = 0; k < 16; k++)
      acc += (a[k] * inv) * bu2f(sm[PES_OFF + (pt * 16 + k) * 264 + m]);
    float val = bu2f(value_t[((size_t)(b * N_ + n0 + pt)) * D_ + m]);
    aggs[m * 4 + pt] = val + acc;
  }
  __syncthreads();

  // ---- Phase 7: linear_end: out[ci][n] = We[ci] . agg[., pt] + bfin ----
  {
    int ci = tid >> 2, pt = tid & 3;
    float acc = scal[SC_BFIN + ci];
    const u16* wr = Weg + (size_t)ci * 256;
    for (int m8 = 0; m8 < 256; m8 += 8) {
      uint4 wu = *(const uint4*)(wr + m8);
      const u16* ws = (const u16*)&wu;
#pragma unroll
      for (int e = 0; e < 8; e++) acc += bu2f(ws[e]) * aggs[(m8 + e) * 4 + pt];
    }
    out[((size_t)(b * 128 + ci)) * N_ + n0 + pt] = acc;
  }
}

// wtmp (f32) offsets
#define WT_LSQ 0
#define WT_LSO 32768
#define WT_K 65536
#define WT_Q 131072
#define WT_V 196608
#define WT_P2 262144
#define WT_A1 278528
#define WT_A2 540672
#define WT_E 802816
#define WT_TOT 835584
// wbf (bf16) offsets
#define WB_QP 0
#define WB_KP 32768
#define WB_VP 65536
#define WB_P2 98304
#define WB_A1 114688
#define WB_A2 376832
#define WB_E 638976
#define WB_TOT 671744

extern "C" void kernel_launch(void* const* d_in, const int* in_sizes, int n_in,
                              void* d_out, int out_size, void* d_ws, size_t ws_size,
                              hipStream_t stream) {
  (void)in_sizes; (void)n_in; (void)out_size;
  char* wsb = (char*)d_ws;
  size_t off = 0;
  auto alloc = [&](size_t bytes) -> void* {
    void* p = wsb + off;
    off = (off + bytes + 255) & ~(size_t)255;
    return p;
  };
  // persistent (~15.6 MB)
  int* flag = (int*)alloc(256);
  int* idx = (int*)alloc((size_t)B_ * N_ * KNN * 4);
  u16* wbf = (u16*)alloc((size_t)WB_TOT * 2);
  float* scal = (float*)alloc((size_t)SC_TOT * 4);
  u16* key_t = (u16*)alloc((size_t)B_ * N_ * D_ * 2);
  u16* query_t = (u16*)alloc((size_t)B_ * N_ * D_ * 2);
  u16* value_t = (u16*)alloc((size_t)B_ * N_ * D_ * 2);
  size_t persist = off;
  size_t avail = (ws_size > persist) ? (ws_size - persist) : 0;

  // overlay (time-disjoint): wtmp -> qp_t/obj_t -> knn_part
  char* ovl = wsb + persist;
  float* wtmp = (float*)ovl;
  u16* qp_t = (u16*)ovl;
  u16* obj_t = (u16*)(ovl + (size_t)B_ * N_ * 128 * 2 + 256);
  u64* knn_part = (u64*)ovl;

  int lognchk = -1;   // -1 => zero-scratch knn_full
  for (int lg = 3; lg >= 0; lg--) {
    if ((((size_t)B_ * N_ * KNN * 8) << lg) <= avail) { lognchk = lg; break; }
  }

  // 1. dtype flag
  detect_dtype<<<1, 256, 0, stream>>>((const unsigned*)d_in[1], flag);

  // 2. ingest canonical f32
  SegTab st;
  int si = 0;
  auto seg = [&](int di, float* d, int n) { st.seg[si].s = d_in[di]; st.seg[si].d = d; st.seg[si].n = n; si++; };
  seg(1, scal + SC_POS, 24576);
  seg(4, scal + SC_BLSQ, 256); seg(6, scal + SC_BLSO, 256);
  seg(8, scal + SC_BK, 256); seg(10, scal + SC_BQ, 256); seg(12, scal + SC_BV, 256);
  seg(13, scal + SC_WP1, 192); seg(14, scal + SC_BP1, 64); seg(15, scal + SC_G1, 64);
  seg(16, scal + SC_BT1, 64); seg(17, scal + SC_M1, 64); seg(18, scal + SC_V1, 64);
  seg(20, scal + SC_BP2, 256); seg(22, scal + SC_BA1, 1024);
  seg(23, scal + SC_G2, 1024); seg(24, scal + SC_BT2, 1024); seg(25, scal + SC_M2, 1024);
  seg(26, scal + SC_V2, 1024); seg(28, scal + SC_BA2, 256); seg(30, scal + SC_BFIN, 128);
  seg(3, wtmp + WT_LSQ, 32768); seg(5, wtmp + WT_LSO, 32768);
  seg(7, wtmp + WT_K, 65536); seg(9, wtmp + WT_Q, 65536); seg(11, wtmp + WT_V, 65536);
  seg(19, wtmp + WT_P2, 16384); seg(21, wtmp + WT_A1, 262144);
  seg(27, wtmp + WT_A2, 262144); seg(29, wtmp + WT_E, 32768);
  int total = 32128 + WT_TOT;
  ingest<<<(total + 255) / 256, 256, 0, stream>>>(st, flag, total);

  // 3. fold BN + compose q/k/v chains + quantize Wp2/Wa1/Wa2/We
  bnprep<<<4, 256, 0, stream>>>(scal);
  compose<<<130, 256, 0, stream>>>(wtmp + WT_Q, wtmp + WT_LSQ, scal + SC_BLSQ, scal + SC_BQ, wbf + WB_QP, scal + SC_BQP);
  compose<<<130, 256, 0, stream>>>(wtmp + WT_K, wtmp + WT_LSO, scal + SC_BLSO, scal + SC_BK, wbf + WB_KP, scal + SC_BKP);
  compose<<<130, 256, 0, stream>>>(wtmp + WT_V, wtmp + WT_LSO, scal + SC_BLSO, scal + SC_BV, wbf + WB_VP, scal + SC_BVP);
  quant<<<(573440 + 255) / 256, 256, 0, stream>>>(wtmp + WT_P2, wbf + WB_P2, 573440);

  // 4. transpose inputs (wtmp dead)
  transq<<<dim3(N_ / 32, 4, B_), 256, 0, stream>>>(d_in[2], qp_t, flag);
  transq<<<dim3(N_ / 32, 4, B_), 256, 0, stream>>>(d_in[0], obj_t, flag);

  // 5. q/k/v projections (composed, K=128)
  gemm_bt<<<dim3(B_ * N_ / 128, 2), 256, 0, stream>>>(wbf + WB_QP, qp_t, query_t, scal + SC_BQP, 256, 128);
  gemm_bt<<<dim3(B_ * N_ / 128, 2), 256, 0, stream>>>(wbf + WB_KP, obj_t, key_t, scal + SC_BKP, 256, 128);
  gemm_bt<<<dim3(B_ * N_ / 128, 2), 256, 0, stream>>>(wbf + WB_VP, obj_t, value_t, scal + SC_BVP, 256, 128);

  // 6. KNN (qp_t/obj_t dead)
  if (lognchk >= 0) {
    knn_partial<<<((B_ * N_) << lognchk) / 256, 256, 0, stream>>>(scal + SC_POS, knn_part, lognchk);
    knn_merge<<<(B_ * N_) / 256, 256, 0, stream>>>(knn_part, idx, lognchk);
  } else {
    knn_full<<<(B_ * N_) / 256, 256, 0, stream>>>(scal + SC_POS, idx);
  }

  // 7. MEGA fused pipeline
  mega<<<COLS_TOTAL / 64, 512, 0, stream>>>(
      scal, idx, wbf, query_t, key_t, value_t, (float*)d_out,
      wbf + WB_P2, wbf + WB_A1, wbf + WB_A2, wbf + WB_E);
}

// Round 7
// 670.916 us; speedup vs baseline: 1.4674x; 1.1730x over previous
//
#include <hip/hip_runtime.h>
#include <stdint.h>

#define B_ 2
#define N_ 4096
#define KNN 16
#define D_ 256
#define EPS_ 1e-5f
#define COLS_TOTAL (B_ * N_ * KNN)   // 131072

typedef unsigned short u16;
typedef unsigned long long u64;
typedef __bf16 bf16x8 __attribute__((ext_vector_type(8)));
typedef float f32x4 __attribute__((ext_vector_type(4)));

__device__ __forceinline__ float bu2f(u16 u) { return __uint_as_float(((unsigned)u) << 16); }
__device__ __forceinline__ u16 f2bu(float f) {
  unsigned u = __float_as_uint(f);
  unsigned r = (u + 0x7FFFu + ((u >> 16) & 1u)) >> 16;   // RNE
  return (u16)r;
}
__device__ __forceinline__ float rdl(const void* p, size_t i, int f) {
  return f ? bu2f(((const u16*)p)[i]) : ((const float*)p)[i];
}
// async global->LDS, 16B per lane; LDS dest MUST be wave-uniform base + lane*16
__device__ __forceinline__ void gl16(const u16* g, u16* l) {
  __builtin_amdgcn_global_load_lds((const __attribute__((address_space(1))) unsigned int*)g,
                                   (__attribute__((address_space(3))) unsigned int*)l,
                                   16, 0, 0);
}

// ---------- dtype detect ----------
__global__ void detect_dtype(const unsigned* __restrict__ p, int* __restrict__ flag) {
  __shared__ int cnt;
  if (threadIdx.x == 0) cnt = 0;
  __syncthreads();
  unsigned w = p[threadIdx.x];
  unsigned e = (w >> 7) & 0xFFu;
  if (e >= 0x7Au && e <= 0x81u) atomicAdd(&cnt, 1);
  __syncthreads();
  if (threadIdx.x == 0) *flag = (cnt >= 128) ? 1 : 0;
}

// ---------- ingest ----------
#define NSEG 29
struct Seg { const void* s; float* d; int n; };
struct SegTab { Seg seg[NSEG]; };
__global__ void ingest(SegTab t, const int* __restrict__ flagp, int total) {
  int tid = blockIdx.x * blockDim.x + threadIdx.x;
  if (tid >= total) return;
  int f = *flagp;
  int acc = 0, k = 0;
  for (k = 0; k < NSEG; k++) { if (tid < acc + t.seg[k].n) break; acc += t.seg[k].n; }
  int i = tid - acc;
  t.seg[k].d[i] = rdl(t.seg[k].s, i, f);
}

// ---------- compose q/k/v chain ----------
__global__ void compose(const float* __restrict__ Wo, const float* __restrict__ Wi,
                        const float* __restrict__ bi, const float* __restrict__ bo,
                        u16* __restrict__ Wout, float* __restrict__ bout) {
  int tid = blockIdx.x * blockDim.x + threadIdx.x;
  if (tid < 256 * 128) {
    int o = tid >> 7, i = tid & 127;
    float a = 0.f;
    for (int d = 0; d < 256; d++) a += Wo[o * 256 + d] * Wi[d * 128 + i];
    Wout[o * 128 + i] = f2bu(a);
  } else if (tid < 256 * 128 + 256) {
    int o = tid - 256 * 128;
    float a = bo[o];
    for (int d = 0; d < 256; d++) a += Wo[o * 256 + d] * bi[d];
    bout[o] = a;
  }
}

__global__ void quant(const float* __restrict__ s, u16* __restrict__ d, int n) {
  int t = blockIdx.x * blockDim.x + threadIdx.x;
  if (t < n) d[t] = f2bu(s[t]);
}

// ---------- scal (canonical f32) offsets ----------
#define SC_POS 0
#define SC_BLSQ 24576
#define SC_BLSO 24832
#define SC_BK 25088
#define SC_BQ 25344
#define SC_BV 25600
#define SC_WP1 25856
#define SC_BP1 26048
#define SC_G1 26112
#define SC_BT1 26176
#define SC_M1 26240
#define SC_V1 26304
#define SC_BP2 26368
#define SC_BA1 26624
#define SC_G2 27648
#define SC_BT2 28672
#define SC_M2 29696
#define SC_V2 30720
#define SC_BA2 31744
#define SC_BFIN 32000
#define SC_BQP 32128
#define SC_BKP 32384
#define SC_BVP 32640
// folded BN constants (bnprep)
#define SC_W1S 32896   // 192: Wp1 * sc1
#define SC_C1  33088   // 64:  bp1*sc1 + (bt1 - m1*sc1)
#define SC_ASC 33152   // 1024: g2/sqrt(v2+eps)
#define SC_ASH 34176   // 1024: ba1*asc + (bt2 - m2*asc)
#define SC_TOT 35200

// ---------- fold BN params ----------
__global__ void bnprep(float* __restrict__ scal) {
  int t = blockIdx.x * blockDim.x + threadIdx.x;
  if (t < 1024) {
    float sc = scal[SC_G2 + t] * (1.0f / sqrtf(scal[SC_V2 + t] + EPS_));
    scal[SC_ASC + t] = sc;
    scal[SC_ASH + t] = scal[SC_BA1 + t] * sc + (scal[SC_BT2 + t] - scal[SC_M2 + t] * sc);
  }
  if (t < 64) {
    float sc1 = scal[SC_G1 + t] * (1.0f / sqrtf(scal[SC_V1 + t] + EPS_));
    scal[SC_C1 + t] = scal[SC_BP1 + t] * sc1 + (scal[SC_BT1 + t] - scal[SC_M1 + t] * sc1);
    for (int i = 0; i < 3; i++) scal[SC_W1S + t * 3 + i] = scal[SC_WP1 + t * 3 + i] * sc1;
  }
}

// ---------- transpose+quantize raw (B,128,N) -> (B*N,128) bf16 ----------
__global__ void transq(const void* __restrict__ raw, u16* __restrict__ out,
                       const int* __restrict__ flagp) {
  __shared__ u16 t[32][33];
  int f = *flagp;
  int b = blockIdx.z, c0 = blockIdx.y * 32, n0 = blockIdx.x * 32;
  int j = threadIdx.x & 31, i0 = threadIdx.x >> 5;
  for (int s = 0; s < 32; s += 8) {
    int i = i0 + s;
    t[i][j] = f2bu(rdl(raw, ((size_t)b * 128 + c0 + i) * N_ + n0 + j, f));
  }
  __syncthreads();
  int i = threadIdx.x & 31, j0 = threadIdx.x >> 5;
  for (int s = 0; s < 32; s += 8) {
    int jj = j0 + s;
    out[((size_t)b * N_ + n0 + jj) * 128 + c0 + i] = t[i][jj];
  }
}

// ---------- KNN ----------
__device__ __forceinline__ void knn_insert(u64* best, u64 key) {
#pragma unroll
  for (int j = 0; j < KNN; j++) {
    u64 old = best[j];
    bool lt = key < old;
    best[j] = lt ? key : old;
    key = lt ? old : key;
  }
}
__device__ __forceinline__ u64 knn_key(const float* px, float qx, float qy, float qz,
                                       float sqn, int m) {
  float cx = px[m], cy = px[N_ + m], cz = px[2 * N_ + m];
  float sqm = cx * cx + cy * cy + cz * cz;
  float dot = qx * cx + qy * cy + qz * cz;
  float d = (sqn + sqm) - 2.0f * dot;
  unsigned ub = __float_as_uint(d);
  ub = ((int)ub < 0) ? ~ub : (ub | 0x80000000u);
  return ((u64)ub << 32) | (unsigned)m;
}

__global__ void knn_partial(const float* __restrict__ pos, u64* __restrict__ part, int lognchk) {
  int nchk = 1 << lognchk;
  int tid = blockIdx.x * blockDim.x + threadIdx.x;
  if (tid >= (B_ * N_) << lognchk) return;
  int n = tid & (N_ - 1);
  int ch = (tid >> 12) & (nchk - 1);
  int b = tid >> (12 + lognchk);
  const float* px = pos + (size_t)b * 3 * N_;
  float qx = px[n], qy = px[N_ + n], qz = px[2 * N_ + n];
  float sqn = qx * qx + qy * qy + qz * qz;
  u64 best[KNN];
#pragma unroll
  for (int i = 0; i < KNN; i++) best[i] = ~0ull;
  int clen = N_ >> lognchk;
  int m0 = ch * clen;
  for (int m = m0; m < m0 + clen; ++m) knn_insert(best, knn_key(px, qx, qy, qz, sqn, m));
  u64* o = part + (size_t)tid * KNN;
#pragma unroll
  for (int i = 0; i < KNN; i++) o[i] = best[i];
}

__global__ void knn_merge(const u64* __restrict__ part, int* __restrict__ idx, int lognchk) {
  int tid = blockIdx.x * blockDim.x + threadIdx.x;
  if (tid >= B_ * N_) return;
  int n = tid & (N_ - 1);
  int b = tid >> 12;
  int nchk = 1 << lognchk;
  u64 best[KNN];
#pragma unroll
  for (int i = 0; i < KNN; i++) best[i] = ~0ull;
  for (int ch = 0; ch < nchk; ch++) {
    const u64* p = part + ((((size_t)((b << lognchk) + ch)) << 12) + n) * KNN;
    for (int e = 0; e < KNN; e++) knn_insert(best, p[e]);
  }
  int* o = idx + (size_t)tid * KNN;
#pragma unroll
  for (int i = 0; i < KNN; i++) o[i] = (int)(best[i] & 0xffffffffu);
}

__global__ void knn_full(const float* __restrict__ pos, int* __restrict__ idx) {
  int tid = blockIdx.x * blockDim.x + threadIdx.x;
  if (tid >= B_ * N_) return;
  int n = tid & (N_ - 1);
  int b = tid >> 12;
  const float* px = pos + (size_t)b * 3 * N_;
  float qx = px[n], qy = px[N_ + n], qz = px[2 * N_ + n];
  float sqn = qx * qx + qy * qy + qz * qz;
  u64 best[KNN];
#pragma unroll
  for (int i = 0; i < KNN; i++) best[i] = ~0ull;
  for (int m = 0; m < N_; ++m) knn_insert(best, knn_key(px, qx, qy, qz, sqn, m));
  int* o = idx + (size_t)tid * KNN;
#pragma unroll
  for (int i = 0; i < KNN; i++) o[i] = (int)(best[i] & 0xffffffffu);
}

// ---------- q/k/v projection GEMM (proven) ----------
__global__ __launch_bounds__(256) void gemm_bt(
    const u16* __restrict__ Wg, const u16* __restrict__ Bg, u16* __restrict__ Out,
    const float* __restrict__ bias, int M, int K) {
  __shared__ __align__(16) u16 As[128 * 32];
  __shared__ __align__(16) u16 Bs[128 * 32];
  const int tid = threadIdx.x;
  const int mtile = blockIdx.y, ctile = blockIdx.x;
  const int wid = tid >> 6, lane = tid & 63;
  const int wm = wid >> 1, wc = wid & 1;
  const int l15 = lane & 15, quad = lane >> 4;
  f32x4 acc[4][4];
#pragma unroll
  for (int a = 0; a < 4; a++)
#pragma unroll
    for (int bb = 0; bb < 4; bb++) acc[a][bb] = (f32x4){0.f, 0.f, 0.f, 0.f};
  const int r0 = tid >> 2, q0 = tid & 3;
  for (int k0 = 0; k0 < K; k0 += 32) {
    __syncthreads();
    *(uint4*)(&As[(r0) * 32 + q0 * 8]) = *(const uint4*)(&Wg[((size_t)mtile * 128 + r0) * K + k0 + q0 * 8]);
    *(uint4*)(&As[(r0 + 64) * 32 + q0 * 8]) = *(const uint4*)(&Wg[((size_t)mtile * 128 + r0 + 64) * K + k0 + q0 * 8]);
    *(uint4*)(&Bs[(r0) * 32 + q0 * 8]) = *(const uint4*)(&Bg[((size_t)ctile * 128 + r0) * K + k0 + q0 * 8]);
    *(uint4*)(&Bs[(r0 + 64) * 32 + q0 * 8]) = *(const uint4*)(&Bg[((size_t)ctile * 128 + r0 + 64) * K + k0 + q0 * 8]);
    __syncthreads();
    bf16x8 af[4], bfr[4];
#pragma unroll
    for (int i = 0; i < 4; i++) {
      af[i] = *(const bf16x8*)(&As[(wm * 64 + i * 16 + l15) * 32 + quad * 8]);
      bfr[i] = *(const bf16x8*)(&Bs[(wc * 64 + i * 16 + l15) * 32 + quad * 8]);
    }
#pragma unroll
    for (int mi = 0; mi < 4; mi++)
#pragma unroll
      for (int ni = 0; ni < 4; ni++)
        acc[mi][ni] = __builtin_amdgcn_mfma_f32_16x16x32_bf16(af[mi], bfr[ni], acc[mi][ni], 0, 0, 0);
  }
  const int mbase = mtile * 128 + wm * 64;
  const int cbase = ctile * 128 + wc * 64;
#pragma unroll
  for (int mi = 0; mi < 4; mi++) {
#pragma unroll
    for (int ni = 0; ni < 4; ni++) {
      int m0 = mbase + mi * 16 + quad * 4;
      int c = cbase + ni * 16 + l15;
      u16 pk[4];
#pragma unroll
      for (int r = 0; r < 4; r++) pk[r] = f2bu(acc[mi][ni][r] + bias[m0 + r]);
      *(uint2*)(&Out[(size_t)c * M + m0]) = *(uint2*)pk;
    }
  }
}

// ================= MEGA v2: LDS <= 72 KB -> 2 blocks/CU =================
// 64 columns (4 points) per block, 512 threads (8 waves).
// LDS u16 offsets (region reuse over time):
//   XS : h1? no -> pe (P2 out) -> X -> attn     64 x 264
//   HS : h1 (phase 0-1) -> h slices (hb loop)   64 x 136
//   WST: weight staging                          8192 u16 (16 KB)
#define XS_OFF  0
#define HS_OFF  16896
#define WST_OFF 25600
#define SM_TOT  33792    // u16 -> 67,584 B (+4 KB aggs = 71,680 B < 80 KB)

__global__ __launch_bounds__(512, 4) void mega(
    const float* __restrict__ scal, const int* __restrict__ idx,
    const u16* __restrict__ query_t, const u16* __restrict__ key_t,
    const u16* __restrict__ value_t, u16* __restrict__ pe_g,
    float* __restrict__ out,
    const u16* __restrict__ Wp2g, const u16* __restrict__ Wa1g,
    const u16* __restrict__ Wa2g, const u16* __restrict__ Weg) {
  __shared__ __align__(16) u16 sm[SM_TOT];
  __shared__ __align__(16) float aggs[1024];   // [m][pt]
  const int tid = threadIdx.x;
  const int w = tid >> 6, lane = tid & 63;
  const int l15 = lane & 15, quad = lane >> 4;
  const int gcol0 = blockIdx.x * 64;
  const int b = gcol0 >> 16;
  const int n0 = (gcol0 & 65535) >> 4;         // 4 points n0..n0+3
  const int wmg = w & 3, wcg = w >> 2;

  // ---- Phase 0: h1 (pos_mlp layer 1, BN folded) -> HS region ----
  {
    int col = tid >> 3, jg = (tid & 7) * 8;
    int n = n0 + (col >> 4), k = col & 15;
    int id = idx[((size_t)(b * N_ + n)) * KNN + k];
    const float* px = scal + SC_POS + (size_t)b * 3 * N_;
    float pr0 = px[n] - px[id];
    float pr1 = px[N_ + n] - px[N_ + id];
    float pr2 = px[2 * N_ + n] - px[2 * N_ + id];
    u16 o[8];
#pragma unroll
    for (int e = 0; e < 8; e++) {
      int j = jg + e;
      float v = scal[SC_W1S + j * 3] * pr0 + scal[SC_W1S + j * 3 + 1] * pr1 +
                scal[SC_W1S + j * 3 + 2] * pr2 + scal[SC_C1 + j];
      o[e] = f2bu(fmaxf(v, 0.f));
    }
    *(uint4*)(&sm[HS_OFF + col * 72 + jg]) = *(uint4*)o;
  }
  __syncthreads();

  // ---- Phase 1: P2 -> pe into XS region ----
  {
    f32x4 pacc[4][2];
#pragma unroll
    for (int mi = 0; mi < 4; mi++)
#pragma unroll
      for (int ni = 0; ni < 2; ni++) pacc[mi][ni] = (f32x4){0.f, 0.f, 0.f, 0.f};
    for (int k0 = 0; k0 < 64; k0 += 32) {
#pragma unroll
      for (int it = 0; it < 2; it++) {
        int c = tid + it * 512;
        int row = c >> 2, sub = c & 3;
        gl16(Wp2g + (size_t)row * 64 + k0 + sub * 8, &sm[WST_OFF + c * 8]);
      }
      __syncthreads();
      bf16x8 bfr[2];
#pragma unroll
      for (int ni = 0; ni < 2; ni++)
        bfr[ni] = *(const bf16x8*)(&sm[HS_OFF + (wcg * 32 + ni * 16 + l15) * 72 + k0 + quad * 8]);
#pragma unroll
      for (int mi = 0; mi < 4; mi++) {
        bf16x8 af = *(const bf16x8*)(&sm[WST_OFF + (wmg * 64 + mi * 16 + l15) * 32 + quad * 8]);
#pragma unroll
        for (int ni = 0; ni < 2; ni++)
          pacc[mi][ni] = __builtin_amdgcn_mfma_f32_16x16x32_bf16(af, bfr[ni], pacc[mi][ni], 0, 0, 0);
      }
      __syncthreads();
    }
#pragma unroll
    for (int mi = 0; mi < 4; mi++)
#pragma unroll
      for (int ni = 0; ni < 2; ni++) {
        int m0 = wmg * 64 + mi * 16 + quad * 4;
        int col = wcg * 32 + ni * 16 + l15;
        u16 pk[4];
#pragma unroll
        for (int r = 0; r < 4; r++) pk[r] = f2bu(pacc[mi][ni][r] + scal[SC_BP2 + m0 + r]);
        *(uint2*)(&sm[XS_OFF + col * 264 + m0]) = *(uint2*)pk;
      }
  }
  __syncthreads();

  // ---- Phase 2: pe -> pe_g (coalesced) ; X = query - key_gather + pe (reg-buffered) ----
  {
    uint4 xbuf[4];
#pragma unroll
    for (int it = 0; it < 4; it++) {
      int g = tid + it * 512;
      int col = g >> 5, dg = (g & 31) * 8;
      int n = n0 + (col >> 4), k = col & 15;
      int id = idx[((size_t)(b * N_ + n)) * KNN + k];
      uint4 pu = *(const uint4*)(&sm[XS_OFF + col * 264 + dg]);
      *(uint4*)(pe_g + ((size_t)(gcol0 + col)) * D_ + dg) = pu;   // coalesced pe spill (L2-hot)
      uint4 qu = *(const uint4*)(query_t + ((size_t)(b * N_ + n)) * D_ + dg);
      uint4 ku = *(const uint4*)(key_t + ((size_t)(b * N_ + id)) * D_ + dg);
      const u16 *qs = (const u16*)&qu, *ks = (const u16*)&ku, *ps = (const u16*)&pu;
      u16 o[8];
#pragma unroll
      for (int e = 0; e < 8; e++) o[e] = f2bu((bu2f(qs[e]) - bu2f(ks[e])) + bu2f(ps[e]));
      xbuf[it] = *(uint4*)o;
    }
    __syncthreads();
#pragma unroll
    for (int it = 0; it < 4; it++) {
      int g = tid + it * 512;
      int col = g >> 5, dg = (g & 31) * 8;
      *(uint4*)(&sm[XS_OFF + col * 264 + dg]) = xbuf[it];
    }
  }
  __syncthreads();

  // ---- Phase 3/4: A1 (h slice) + A2 accumulate, per 128-row h block ----
  f32x4 aacc[4][2];
#pragma unroll
  for (int mi = 0; mi < 4; mi++)
#pragma unroll
    for (int ni = 0; ni < 2; ni++) aacc[mi][ni] = (f32x4){0.f, 0.f, 0.f, 0.f};

  for (int hb = 0; hb < 8; hb++) {
    f32x4 hacc[2][2];
#pragma unroll
    for (int mi = 0; mi < 2; mi++)
#pragma unroll
      for (int ni = 0; ni < 2; ni++) hacc[mi][ni] = (f32x4){0.f, 0.f, 0.f, 0.f};
    for (int k0 = 0; k0 < 256; k0 += 32) {
      {
        int row = tid >> 2, sub = tid & 3;
        gl16(Wa1g + ((size_t)(hb * 128 + row)) * 256 + k0 + sub * 8, &sm[WST_OFF + tid * 8]);
      }
      __syncthreads();
      bf16x8 bx[2];
#pragma unroll
      for (int ni = 0; ni < 2; ni++)
        bx[ni] = *(const bf16x8*)(&sm[XS_OFF + (wcg * 32 + ni * 16 + l15) * 264 + k0 + quad * 8]);
#pragma unroll
      for (int mi = 0; mi < 2; mi++) {
        bf16x8 af = *(const bf16x8*)(&sm[WST_OFF + (wmg * 32 + mi * 16 + l15) * 32 + quad * 8]);
#pragma unroll
        for (int ni = 0; ni < 2; ni++)
          hacc[mi][ni] = __builtin_amdgcn_mfma_f32_16x16x32_bf16(af, bx[ni], hacc[mi][ni], 0, 0, 0);
      }
      __syncthreads();
    }
    // h epilogue: folded BN+ReLU -> HS
#pragma unroll
    for (int mi = 0; mi < 2; mi++)
#pragma unroll
      for (int ni = 0; ni < 2; ni++) {
        int hr0 = wmg * 32 + mi * 16 + quad * 4;
        int mh = hb * 128 + hr0;
        int col = wcg * 32 + ni * 16 + l15;
        u16 pk[4];
#pragma unroll
        for (int r = 0; r < 4; r++) {
          float v = hacc[mi][ni][r] * scal[SC_ASC + mh + r] + scal[SC_ASH + mh + r];
          pk[r] = f2bu(fmaxf(v, 0.f));
        }
        *(uint2*)(&sm[HS_OFF + col * 136 + hr0]) = *(uint2*)pk;
      }
    __syncthreads();
    // A2 over this h block (K=128)
    for (int k0 = 0; k0 < 128; k0 += 32) {
#pragma unroll
      for (int it = 0; it < 2; it++) {
        int c = tid + it * 512;
        int row = c >> 2, sub = c & 3;
        gl16(Wa2g + (size_t)row * 1024 + hb * 128 + k0 + sub * 8, &sm[WST_OFF + c * 8]);
      }
      __syncthreads();
      bf16x8 bh[2];
#pragma unroll
      for (int ni = 0; ni < 2; ni++)
        bh[ni] = *(const bf16x8*)(&sm[HS_OFF + (wcg * 32 + ni * 16 + l15) * 136 + k0 + quad * 8]);
#pragma unroll
      for (int mi = 0; mi < 4; mi++) {
        bf16x8 af = *(const bf16x8*)(&sm[WST_OFF + (wmg * 64 + mi * 16 + l15) * 32 + quad * 8]);
#pragma unroll
        for (int ni = 0; ni < 2; ni++)
          aacc[mi][ni] = __builtin_amdgcn_mfma_f32_16x16x32_bf16(af, bh[ni], aacc[mi][ni], 0, 0, 0);
      }
      __syncthreads();
    }
  }

  // ---- Phase 5: attn (+ba2) -> XS region (X dead) ----
#pragma unroll
  for (int mi = 0; mi < 4; mi++)
#pragma unroll
    for (int ni = 0; ni < 2; ni++) {
      int m0 = wmg * 64 + mi * 16 + quad * 4;
      int col = wcg * 32 + ni * 16 + l15;
      u16 pk[4];
#pragma unroll
      for (int r = 0; r < 4; r++) pk[r] = f2bu(aacc[mi][ni][r] + scal[SC_BA2 + m0 + r]);
      *(uint2*)(&sm[XS_OFF + col * 264 + m0]) = *(uint2*)pk;
    }
  __syncthreads();

  // ---- Phase 6: softmax over 16 neighbors + aggregate (pe from pe_g, L2-hot) ----
#pragma unroll
  for (int it = 0; it < 2; it++) {
    int e = tid + it * 512;          // 1024 = 256 m x 4 pt
    int m = e >> 2, pt = e & 3;
    float a[16];
#pragma unroll
    for (int k = 0; k < 16; k++) a[k] = bu2f(sm[XS_OFF + (pt * 16 + k) * 264 + m]);
    float mx = a[0];
#pragma unroll
    for (int k = 1; k < 16; k++) mx = fmaxf(mx, a[k]);
    float s = 0.f;
#pragma unroll
    for (int k = 0; k < 16; k++) { a[k] = expf(a[k] - mx); s += a[k]; }
    float inv = 1.0f / s;
    float acc = 0.f;
#pragma unroll
    for (int k = 0; k < 16; k++)
      acc += (a[k] * inv) * bu2f(pe_g[((size_t)(gcol0 + pt * 16 + k)) * D_ + m]);
    float val = bu2f(value_t[((size_t)(b * N_ + n0 + pt)) * D_ + m]);
    aggs[m * 4 + pt] = val + acc;
  }
  __syncthreads();

  // ---- Phase 7: linear_end ----
  {
    int ci = tid >> 2, pt = tid & 3;
    float acc = scal[SC_BFIN + ci];
    const u16* wr = Weg + (size_t)ci * 256;
    for (int m8 = 0; m8 < 256; m8 += 8) {
      uint4 wu = *(const uint4*)(wr + m8);
      const u16* ws = (const u16*)&wu;
#pragma unroll
      for (int e = 0; e < 8; e++) acc += bu2f(ws[e]) * aggs[(m8 + e) * 4 + pt];
    }
    out[((size_t)(b * 128 + ci)) * N_ + n0 + pt] = acc;
  }
}

// wtmp (f32) offsets
#define WT_LSQ 0
#define WT_LSO 32768
#define WT_K 65536
#define WT_Q 131072
#define WT_V 196608
#define WT_P2 262144
#define WT_A1 278528
#define WT_A2 540672
#define WT_E 802816
#define WT_TOT 835584
// wbf (bf16) offsets
#define WB_QP 0
#define WB_KP 32768
#define WB_VP 65536
#define WB_P2 98304
#define WB_A1 114688
#define WB_A2 376832
#define WB_E 638976
#define WB_TOT 671744

extern "C" void kernel_launch(void* const* d_in, const int* in_sizes, int n_in,
                              void* d_out, int out_size, void* d_ws, size_t ws_size,
                              hipStream_t stream) {
  (void)in_sizes; (void)n_in; (void)out_size;
  char* wsb = (char*)d_ws;
  size_t off = 0;
  auto alloc = [&](size_t bytes) -> void* {
    void* p = wsb + off;
    off = (off + bytes + 255) & ~(size_t)255;
    return p;
  };
  // persistent (~83 MB incl. pe_g)
  int* flag = (int*)alloc(256);
  int* idx = (int*)alloc((size_t)B_ * N_ * KNN * 4);
  u16* wbf = (u16*)alloc((size_t)WB_TOT * 2);
  float* scal = (float*)alloc((size_t)SC_TOT * 4);
  u16* key_t = (u16*)alloc((size_t)B_ * N_ * D_ * 2);
  u16* query_t = (u16*)alloc((size_t)B_ * N_ * D_ * 2);
  u16* value_t = (u16*)alloc((size_t)B_ * N_ * D_ * 2);
  u16* pe_g = (u16*)alloc((size_t)COLS_TOTAL * D_ * 2);   // 67 MB
  size_t persist = off;
  size_t avail = (ws_size > persist) ? (ws_size - persist) : 0;

  // overlay (time-disjoint): wtmp -> qp_t/obj_t -> knn_part
  char* ovl = wsb + persist;
  float* wtmp = (float*)ovl;
  u16* qp_t = (u16*)ovl;
  u16* obj_t = (u16*)(ovl + (size_t)B_ * N_ * 128 * 2 + 256);
  u64* knn_part = (u64*)ovl;

  int lognchk = -1;   // -1 => zero-scratch knn_full
  for (int lg = 3; lg >= 0; lg--) {
    if ((((size_t)B_ * N_ * KNN * 8) << lg) <= avail) { lognchk = lg; break; }
  }

  // 1. dtype flag
  detect_dtype<<<1, 256, 0, stream>>>((const unsigned*)d_in[1], flag);

  // 2. ingest canonical f32
  SegTab st;
  int si = 0;
  auto seg = [&](int di, float* d, int n) { st.seg[si].s = d_in[di]; st.seg[si].d = d; st.seg[si].n = n; si++; };
  seg(1, scal + SC_POS, 24576);
  seg(4, scal + SC_BLSQ, 256); seg(6, scal + SC_BLSO, 256);
  seg(8, scal + SC_BK, 256); seg(10, scal + SC_BQ, 256); seg(12, scal + SC_BV, 256);
  seg(13, scal + SC_WP1, 192); seg(14, scal + SC_BP1, 64); seg(15, scal + SC_G1, 64);
  seg(16, scal + SC_BT1, 64); seg(17, scal + SC_M1, 64); seg(18, scal + SC_V1, 64);
  seg(20, scal + SC_BP2, 256); seg(22, scal + SC_BA1, 1024);
  seg(23, scal + SC_G2, 1024); seg(24, scal + SC_BT2, 1024); seg(25, scal + SC_M2, 1024);
  seg(26, scal + SC_V2, 1024); seg(28, scal + SC_BA2, 256); seg(30, scal + SC_BFIN, 128);
  seg(3, wtmp + WT_LSQ, 32768); seg(5, wtmp + WT_LSO, 32768);
  seg(7, wtmp + WT_K, 65536); seg(9, wtmp + WT_Q, 65536); seg(11, wtmp + WT_V, 65536);
  seg(19, wtmp + WT_P2, 16384); seg(21, wtmp + WT_A1, 262144);
  seg(27, wtmp + WT_A2, 262144); seg(29, wtmp + WT_E, 32768);
  int total = 32128 + WT_TOT;
  ingest<<<(total + 255) / 256, 256, 0, stream>>>(st, flag, total);

  // 3. fold BN + compose q/k/v chains + quantize Wp2/Wa1/Wa2/We
  bnprep<<<4, 256, 0, stream>>>(scal);
  compose<<<130, 256, 0, stream>>>(wtmp + WT_Q, wtmp + WT_LSQ, scal + SC_BLSQ, scal + SC_BQ, wbf + WB_QP, scal + SC_BQP);
  compose<<<130, 256, 0, stream>>>(wtmp + WT_K, wtmp + WT_LSO, scal + SC_BLSO, scal + SC_BK, wbf + WB_KP, scal + SC_BKP);
  compose<<<130, 256, 0, stream>>>(wtmp + WT_V, wtmp + WT_LSO, scal + SC_BLSO, scal + SC_BV, wbf + WB_VP, scal + SC_BVP);
  quant<<<(573440 + 255) / 256, 256, 0, stream>>>(wtmp + WT_P2, wbf + WB_P2, 573440);

  // 4. transpose inputs (wtmp dead)
  transq<<<dim3(N_ / 32, 4, B_), 256, 0, stream>>>(d_in[2], qp_t, flag);
  transq<<<dim3(N_ / 32, 4, B_), 256, 0, stream>>>(d_in[0], obj_t, flag);

  // 5. q/k/v projections (composed, K=128)
  gemm_bt<<<dim3(B_ * N_ / 128, 2), 256, 0, stream>>>(wbf + WB_QP, qp_t, query_t, scal + SC_BQP, 256, 128);
  gemm_bt<<<dim3(B_ * N_ / 128, 2), 256, 0, stream>>>(wbf + WB_KP, obj_t, key_t, scal + SC_BKP, 256, 128);
  gemm_bt<<<dim3(B_ * N_ / 128, 2), 256, 0, stream>>>(wbf + WB_VP, obj_t, value_t, scal + SC_BVP, 256, 128);

  // 6. KNN (qp_t/obj_t dead)
  if (lognchk >= 0) {
    knn_partial<<<((B_ * N_) << lognchk) / 256, 256, 0, stream>>>(scal + SC_POS, knn_part, lognchk);
    knn_merge<<<(B_ * N_) / 256, 256, 0, stream>>>(knn_part, idx, lognchk);
  } else {
    knn_full<<<(B_ * N_) / 256, 256, 0, stream>>>(scal + SC_POS, idx);
  }

  // 7. MEGA fused pipeline (2 blocks/CU)
  mega<<<COLS_TOTAL / 64, 512, 0, stream>>>(
      scal, idx, query_t, key_t, value_t, pe_g, (float*)d_out,
      wbf + WB_P2, wbf + WB_A1, wbf + WB_A2, wbf + WB_E);
}